// Round 5
// baseline (23192.163 us; speedup 1.0000x reference)
//
#include <hip/hip_runtime.h>
#include <math.h>

// Problem dims (fixed)
#define B_ 2
#define C_ 2048
#define M_ 1024
#define H_ 16
#define KV_ 64
#define F_ 4096

__device__ __forceinline__ float bf2f(unsigned short u) {
    union { unsigned int i; float f; } x; x.i = ((unsigned int)u) << 16; return x.f;
}
__device__ __forceinline__ unsigned short f2bf(float f) {
    union { float f; unsigned int i; } x; x.f = f;
    unsigned int r = x.i + 0x7fffu + ((x.i >> 16) & 1u);
    return (unsigned short)(r >> 16);
}
// flag-adaptive scalar load: isf ? fp32 : bf16
__device__ __forceinline__ float ldflag(const void* p, size_t i, int isf) {
    return isf ? ((const float*)p)[i] : bf2f(((const unsigned short*)p)[i]);
}

__device__ __forceinline__ double blockReduceSumD(double v, double* red, int tid) {
#pragma unroll
    for (int off = 32; off > 0; off >>= 1) v += __shfl_down(v, off, 64);
    if ((tid & 63) == 0) red[tid >> 6] = v;
    __syncthreads();
    v = red[0] + red[1] + red[2] + red[3];
    __syncthreads();
    return v;
}

// ---------------------------------------------------------------------------
// Input-dtype detector (fires fp32 on this harness; kept for safety).
// flags[0]=1 iff inputs are fp32.
// ---------------------------------------------------------------------------
__global__ void detect_dtype(const unsigned int* __restrict__ w, int* __restrict__ flags) {
    __shared__ int cnt[256];
    int t = threadIdx.x, c = 0;
    for (int i = t; i < 2048; i += 256) {
        unsigned int e = (w[i] >> 7) & 0xffu;
        if (e >= 140u || (e > 0u && e < 91u)) c++;
    }
    cnt[t] = c; __syncthreads();
    for (int s = 128; s > 0; s >>= 1) { if (t < s) cnt[t] += cnt[t + s]; __syncthreads(); }
    if (t == 0) flags[0] = (cnt[0] > 300) ? 1 : 0;
}

// ---------------------------------------------------------------------------
// fp64-arithmetic GEMM: C[M,N] = A[M,Kd]*B[Kd,N] (+bias, relu), fp64 accum,
// fp32 storage. AMODE: 0 = flag-dtype input, 1 = fp32 intermediate.
// B is always a flag-dtype input tensor. Tile 64x64x32, 16x16 thr x 4x4.
// ---------------------------------------------------------------------------
template<int AMODE, bool RELU, bool BIAS>
__global__ __launch_bounds__(256) void proj_f64(
    const void* __restrict__ Ab, const void* __restrict__ Bb,
    float* __restrict__ Cb, const void* __restrict__ bias,
    const int* __restrict__ flags,
    int N, int Kd, long long a_bstr, long long b_hstr, long long c_zstr, int NH)
{
    const int isf = flags[0];
    const int isfA = (AMODE == 1) ? 1 : isf;
    __shared__ double Ast[32][65];   // [k][m] (transposed on stage)  16.6 KB
    __shared__ double Bs[32][65];    // [k][n]                        16.6 KB
    const int t = threadIdx.x;
    const int m0 = blockIdx.x * 64, n0 = blockIdx.y * 64;
    const int zb = blockIdx.z / NH, zh = blockIdx.z % NH;
    const size_t aoff = (size_t)zb * a_bstr, boff = (size_t)zh * b_hstr;

    double acc[4][4] = {};
    const int ar = t >> 2, ak = (t & 3) * 8;   // A: row m0+ar, k chunk of 8
    const int bk = t >> 3, bn = (t & 7) * 8;   // B: k row bk, n chunk of 8

    for (int k0 = 0; k0 < Kd; k0 += 32) {
        double av[8];
        {
            size_t off = aoff + (size_t)(m0 + ar) * Kd + k0 + ak;
            if (isfA) {
                const float* ap = (const float*)Ab + off;
                float4 p0 = *(const float4*)ap, p1 = *((const float4*)ap + 1);
                av[0]=p0.x; av[1]=p0.y; av[2]=p0.z; av[3]=p0.w;
                av[4]=p1.x; av[5]=p1.y; av[6]=p1.z; av[7]=p1.w;
            } else {
                const unsigned short* ap = (const unsigned short*)Ab + off;
                int4 p = *(const int4*)ap;
                unsigned int u[4] = {(unsigned)p.x,(unsigned)p.y,(unsigned)p.z,(unsigned)p.w};
#pragma unroll
                for (int j = 0; j < 4; j++) {
                    av[2*j]   = (double)bf2f((unsigned short)(u[j] & 0xffffu));
                    av[2*j+1] = (double)bf2f((unsigned short)(u[j] >> 16));
                }
            }
        }
#pragma unroll
        for (int j = 0; j < 8; j++) Ast[ak + j][ar] = av[j];
        double bv[8];
        {
            size_t off = boff + (size_t)(k0 + bk) * N + n0 + bn;
            if (isf) {
                const float* bp = (const float*)Bb + off;
                float4 p0 = *(const float4*)bp, p1 = *((const float4*)bp + 1);
                bv[0]=p0.x; bv[1]=p0.y; bv[2]=p0.z; bv[3]=p0.w;
                bv[4]=p1.x; bv[5]=p1.y; bv[6]=p1.z; bv[7]=p1.w;
            } else {
                const unsigned short* bp = (const unsigned short*)Bb + off;
                int4 p = *(const int4*)bp;
                unsigned int u[4] = {(unsigned)p.x,(unsigned)p.y,(unsigned)p.z,(unsigned)p.w};
#pragma unroll
                for (int j = 0; j < 4; j++) {
                    bv[2*j]   = (double)bf2f((unsigned short)(u[j] & 0xffffu));
                    bv[2*j+1] = (double)bf2f((unsigned short)(u[j] >> 16));
                }
            }
        }
#pragma unroll
        for (int j = 0; j < 8; j++) Bs[bk][bn + j] = bv[j];
        __syncthreads();
        const int r0 = (t & 15) * 4, c0 = (t >> 4) * 4;
#pragma unroll
        for (int kk = 0; kk < 32; kk++) {
            double a0 = Ast[kk][r0], a1 = Ast[kk][r0+1], a2 = Ast[kk][r0+2], a3 = Ast[kk][r0+3];
            double b0 = Bs[kk][c0], b1 = Bs[kk][c0+1], b2 = Bs[kk][c0+2], b3 = Bs[kk][c0+3];
            acc[0][0] += a0*b0; acc[0][1] += a0*b1; acc[0][2] += a0*b2; acc[0][3] += a0*b3;
            acc[1][0] += a1*b0; acc[1][1] += a1*b1; acc[1][2] += a1*b2; acc[1][3] += a1*b3;
            acc[2][0] += a2*b0; acc[2][1] += a2*b1; acc[2][2] += a2*b2; acc[2][3] += a2*b3;
            acc[3][0] += a3*b0; acc[3][1] += a3*b1; acc[3][2] += a3*b2; acc[3][3] += a3*b3;
        }
        __syncthreads();
    }
    const int r0 = (t & 15) * 4, c0 = (t >> 4) * 4;
    const size_t czoff = (size_t)blockIdx.z * c_zstr;
#pragma unroll
    for (int j = 0; j < 4; j++) {
        double bvv = BIAS ? (double)ldflag(bias, n0 + c0 + j, isf) : 0.0;
#pragma unroll
        for (int i = 0; i < 4; i++) {
            double val = acc[i][j] + bvv;
            if (RELU) val = val > 0.0 ? val : 0.0;
            Cb[czoff + (size_t)(m0 + r0 + i) * N + n0 + c0 + j] = (float)val;
        }
    }
}

// ---------------------------------------------------------------------------
// fp64 attention: block = 4 query rows of one (b,h); wave w owns row d0+w.
// Two-sweep: (1) fp64 logits -> row max (logits discarded); (2) recompute,
// p = exp(0.125*(s-m)) in fp64, stash p as fp32 (p<=1, no cancellation),
// accumulate S in fp64; (3) P*V in fp64, divide by S, store fp32.
// Mask quirk faithful: -100 on UNSCALED logit when c <= d.
// ---------------------------------------------------------------------------
__global__ __launch_bounds__(256) void attn_f64(
    const float* __restrict__ q, const float* __restrict__ k,
    const float* __restrict__ v, float* __restrict__ pre, int masked)
{
    __shared__ float  sp[4][C_];    // 32 KB: softmax numerators
    __shared__ double sqd[4][KV_];  // 2 KB: Q rows in fp64

    const int idx = blockIdx.x;
    const int d0 = (idx & (C_ / 4 - 1)) * 4;
    const int h = (idx >> 9) & (H_ - 1);
    const int b = idx >> 13;
    const size_t bh = (size_t)(b * H_ + h);
    const float* Q = q + (bh * C_ + d0) * KV_;
    const float* K = k + bh * C_ * KV_;
    const float* V = v + bh * C_ * KV_;
    const int tid = threadIdx.x;
    const int w = tid >> 6, l = tid & 63;
    const int d = d0 + w;

    sqd[w][l] = (double)Q[w * KV_ + l];
    __syncthreads();

    // sweep 1: row max
    double m = -1e300;
    for (int c = l; c < C_; c += 64) {
        const float* Kr = K + (size_t)c * KV_;
        double s = 0.0;
#pragma unroll 8
        for (int j = 0; j < KV_; j++) s += (double)Kr[j] * sqd[w][j];
        if (masked && c <= d) s -= 100.0;
        m = fmax(m, s);
    }
#pragma unroll
    for (int off = 32; off > 0; off >>= 1) m = fmax(m, __shfl_down(m, off, 64));
    m = __shfl(m, 0, 64);

    // sweep 2: p + S
    double S = 0.0;
    for (int c = l; c < C_; c += 64) {
        const float* Kr = K + (size_t)c * KV_;
        double s = 0.0;
#pragma unroll 8
        for (int j = 0; j < KV_; j++) s += (double)Kr[j] * sqd[w][j];
        if (masked && c <= d) s -= 100.0;
        double p = exp(0.125 * (s - m));
        S += p;
        sp[w][c] = (float)p;
    }
#pragma unroll
    for (int off = 32; off > 0; off >>= 1) S += __shfl_down(S, off, 64);
    S = __shfl(S, 0, 64);

    __syncthreads();
    // sweep 3: P*V, lane = v column
    double o = 0.0;
    for (int c = 0; c < C_; c++)
        o += (double)sp[w][c] * (double)V[(size_t)c * KV_ + l];
    o /= S;
    pre[(((size_t)b * C_ + d) * H_ + h) * KV_ + l] = (float)o;
}

// ---------------------------------------------------------------------------
// Residual + LayerNorm, fp64 stats/arithmetic, fp32 storage. In-place safe
// (out may alias in1 or in2: row fully read into LDS before writes).
// IN1MODE: 0 = flag-dtype input, 1 = fp32 intermediate.
// OUTMODE: 0 = fp32, 1 = flag-dtype (for d_out).
// ---------------------------------------------------------------------------
template<int IN1MODE, int OUTMODE>
__global__ __launch_bounds__(256) void ln_f64(
    const void* __restrict__ in1, const float* __restrict__ in2,
    const void* __restrict__ g, const void* __restrict__ b,
    void* __restrict__ out, const int* __restrict__ flags)
{
    __shared__ double buf[M_];   // 8 KB
    __shared__ double red[4];
    const int isf = flags[0];
    const int row = blockIdx.x;
    const size_t base = (size_t)row * M_;
    const int tid = threadIdx.x;
    double s = 0.0;
    for (int i = tid; i < M_; i += 256) {
        double v1 = (IN1MODE == 1) ? (double)((const float*)in1)[base + i]
                                   : (double)ldflag(in1, base + i, isf);
        double val = v1 + (double)in2[base + i];
        buf[i] = val;
        s += val;
    }
    s = blockReduceSumD(s, red, tid);
    const double mu = s * (1.0 / M_);
    double vs = 0.0;
    for (int i = tid; i < M_; i += 256) { double dd = buf[i] - mu; vs += dd * dd; }
    vs = blockReduceSumD(vs, red, tid);
    const double rstd = 1.0 / sqrt(vs * (1.0 / M_) + 1e-5);
    for (int i = tid; i < M_; i += 256) {
        double y = (buf[i] - mu) * rstd * (double)ldflag(g, i, isf) + (double)ldflag(b, i, isf);
        if (OUTMODE == 0) ((float*)out)[base + i] = (float)y;
        else if (isf)     ((float*)out)[base + i] = (float)y;
        else              ((unsigned short*)out)[base + i] = f2bf((float)y);
    }
}

// ---------------------------------------------------------------------------
extern "C" void kernel_launch(void* const* d_in, const int* in_sizes, int n_in,
                              void* d_out, int out_size, void* d_ws, size_t ws_size,
                              hipStream_t stream)
{
    const void* enc = d_in[0];
    const void* x   = d_in[1];
    const void* wq1 = d_in[2];
    const void* wk1 = d_in[3];
    const void* wv1 = d_in[4];
    const void* wo1 = d_in[5];
    const void* g1  = d_in[6];
    const void* b1  = d_in[7];
    const void* wq2 = d_in[8];
    const void* wk2 = d_in[9];
    const void* wv2 = d_in[10];
    const void* wo2 = d_in[11];
    const void* g2  = d_in[12];
    const void* b2  = d_in[13];
    const void* fw1 = d_in[14];
    const void* fb1 = d_in[15];
    const void* fw2 = d_in[16];
    const void* fb2 = d_in[17];
    const void* g3  = d_in[18];
    const void* b3  = d_in[19];

    int* fl = (int*)d_ws;                              // flags in first 4 KB
    const size_t NQ = (size_t)B_ * C_ * M_;            // 4,194,304
    // 5 fp32 slots (84 MB total). Lifetimes:
    // S0: q1/q2        -> h1[0]
    // S1: k1 -> attout1 -> k2 -> attout2 -> h1[1]
    // S2: v1 -> v2     -> h1[2]
    // S3: pre1 -> pre2 -> h1[3]
    // S4: n1 -> n2 (LN2 in-place)
    // ff lives in d_out (16.8 MB), LN3 in-place on d_out.
    float* S0 = (float*)((char*)d_ws + 4096);
    float* S1 = S0 + NQ;
    float* S2 = S1 + NQ;
    float* S3 = S2 + NQ;
    float* S4 = S3 + NQ;
    float* q = S0, *kk = S1, *vv = S2, *pre = S3, *attout = S1, *n1 = S4, *n2 = S4;
    float* h1 = S0;                                    // fp32 [4096,4096] = S0..S3
    float* ff = (float*)d_out;                         // scratch in output buffer

    dim3 blk(256);
    dim3 gproj(C_ / 64, KV_ / 64, B_ * H_);            // (32,1,32)
    dim3 gout(B_ * C_ / 64, M_ / 64, 1);               // (64,16,1)
    dim3 gffn1(B_ * C_ / 64, F_ / 64, 1);              // (64,64,1)
    dim3 gffn2(B_ * C_ / 64, M_ / 64, 1);              // (64,16,1)
    dim3 gattn(B_ * H_ * (C_ / 4));                    // 16384
    dim3 gln(B_ * C_);                                 // 4096
    const long long AB = (long long)C_ * M_, BH = (long long)M_ * KV_, CZ = (long long)C_ * KV_;

    detect_dtype<<<1, 256, 0, stream>>>((const unsigned int*)wq1, fl);

    // ---- self-attention (masked) ----
    proj_f64<0,false,false><<<gproj, blk, 0, stream>>>(x, wq1, q,  nullptr, fl, KV_, M_, AB, BH, CZ, H_);
    proj_f64<0,false,false><<<gproj, blk, 0, stream>>>(x, wk1, kk, nullptr, fl, KV_, M_, AB, BH, CZ, H_);
    proj_f64<0,false,false><<<gproj, blk, 0, stream>>>(x, wv1, vv, nullptr, fl, KV_, M_, AB, BH, CZ, H_);
    attn_f64<<<gattn, blk, 0, stream>>>(q, kk, vv, pre, 1);
    proj_f64<1,false,false><<<gout, blk, 0, stream>>>(pre, wo1, attout, nullptr, fl, M_, M_, 0, 0, 0, 1);
    ln_f64<0, 0><<<gln, blk, 0, stream>>>(x, attout, g1, b1, n1, fl);

    // ---- cross-attention ----
    proj_f64<1,false,false><<<gproj, blk, 0, stream>>>(n1, wq2, q,  nullptr, fl, KV_, M_, AB, BH, CZ, H_);
    proj_f64<0,false,false><<<gproj, blk, 0, stream>>>(enc, wk2, kk, nullptr, fl, KV_, M_, AB, BH, CZ, H_);
    proj_f64<0,false,false><<<gproj, blk, 0, stream>>>(enc, wv2, vv, nullptr, fl, KV_, M_, AB, BH, CZ, H_);
    attn_f64<<<gattn, blk, 0, stream>>>(q, kk, vv, pre, 0);
    proj_f64<1,false,false><<<gout, blk, 0, stream>>>(pre, wo2, attout, nullptr, fl, M_, M_, 0, 0, 0, 1);
    ln_f64<1, 0><<<gln, blk, 0, stream>>>(n1, attout, g2, b2, n2, fl);   // in-place S4

    // ---- FFN (h1 fp32 in S0..S3; ff in d_out; LN3 in-place on d_out) ----
    proj_f64<1,true,true><<<gffn1, blk, 0, stream>>>(n2, fw1, h1, fb1, fl, F_, M_, 0, 0, 0, 1);
    proj_f64<1,false,true><<<gffn2, blk, 0, stream>>>(h1, fw2, ff, fb2, fl, M_, F_, 0, 0, 0, 1);
    ln_f64<1, 1><<<gln, blk, 0, stream>>>(n2, ff, g3, b3, d_out, fl);
}

// Round 6
// 7636.143 us; speedup vs baseline: 3.0372x; 3.0372x over previous
//
#include <hip/hip_runtime.h>
#include <math.h>

// Problem dims (fixed)
#define B_ 2
#define C_ 2048
#define M_ 1024
#define H_ 16
#define KV_ 64
#define F_ 4096

typedef __attribute__((ext_vector_type(8))) __bf16 bf16x8;
typedef __attribute__((ext_vector_type(4))) float f32x4;

__device__ __forceinline__ float bf2f(unsigned short u) {
    union { unsigned int i; float f; } x; x.i = ((unsigned int)u) << 16; return x.f;
}
__device__ __forceinline__ unsigned short f2bf(float f) {
    union { float f; unsigned int i; } x; x.f = f;
    unsigned int r = x.i + 0x7fffu + ((x.i >> 16) & 1u);
    return (unsigned short)(r >> 16);
}
__device__ __forceinline__ float ldflag(const void* p, size_t i, int isf) {
    return isf ? ((const float*)p)[i] : bf2f(((const unsigned short*)p)[i]);
}

__device__ __forceinline__ double blockReduceSumD(double v, double* red, int tid) {
#pragma unroll
    for (int off = 32; off > 0; off >>= 1) v += __shfl_down(v, off, 64);
    if ((tid & 63) == 0) red[tid >> 6] = v;
    __syncthreads();
    v = red[0] + red[1] + red[2] + red[3];
    __syncthreads();
    return v;
}

// ---------------------------------------------------------------------------
// Input-dtype detector (fires fp32 on this harness). flags[0]=1 iff fp32.
// ---------------------------------------------------------------------------
__global__ void detect_dtype(const unsigned int* __restrict__ w, int* __restrict__ flags) {
    __shared__ int cnt[256];
    int t = threadIdx.x, c = 0;
    for (int i = t; i < 2048; i += 256) {
        unsigned int e = (w[i] >> 7) & 0xffu;
        if (e >= 140u || (e > 0u && e < 91u)) c++;
    }
    cnt[t] = c; __syncthreads();
    for (int s = 128; s > 0; s >>= 1) { if (t < s) cnt[t] += cnt[t + s]; __syncthreads(); }
    if (t == 0) flags[0] = (cnt[0] > 300) ? 1 : 0;
}

// ---------------------------------------------------------------------------
// Q/K projection GEMM: fp64 ACCUMULATION, fp32 LDS tiles (kills the round-5
// bank conflicts: fp64 LDS stride-65 doubles was 1.3e8 conflict-cycles).
// AMODE: 0 = flag-dtype input, 1 = fp32 intermediate. Output fp32.
// Tile 64x64x32, 16x16 threads x 4x4 each.
// ---------------------------------------------------------------------------
template<int AMODE>
__global__ __launch_bounds__(256) void proj_qk64(
    const void* __restrict__ Ab, const void* __restrict__ Bb,
    float* __restrict__ Cb, const int* __restrict__ flags,
    int N, int Kd, long long a_bstr, long long b_hstr, long long c_zstr, int NH)
{
    const int isf = flags[0];
    const int isfA = (AMODE == 1) ? 1 : isf;
    __shared__ float Ast[32][65];   // [k][m]
    __shared__ float Bs[32][65];    // [k][n]
    const int t = threadIdx.x;
    const int m0 = blockIdx.x * 64, n0 = blockIdx.y * 64;
    const int zb = blockIdx.z / NH, zh = blockIdx.z % NH;
    const size_t aoff = (size_t)zb * a_bstr, boff = (size_t)zh * b_hstr;

    double acc[4][4] = {};
    const int ar = t >> 2, ak = (t & 3) * 8;
    const int bk = t >> 3, bn = (t & 7) * 8;

    for (int k0 = 0; k0 < Kd; k0 += 32) {
        float av[8];
        {
            size_t off = aoff + (size_t)(m0 + ar) * Kd + k0 + ak;
            if (isfA) {
                const float* ap = (const float*)Ab + off;
                float4 p0 = *(const float4*)ap, p1 = *((const float4*)ap + 1);
                av[0]=p0.x; av[1]=p0.y; av[2]=p0.z; av[3]=p0.w;
                av[4]=p1.x; av[5]=p1.y; av[6]=p1.z; av[7]=p1.w;
            } else {
                const unsigned short* ap = (const unsigned short*)Ab + off;
                int4 p = *(const int4*)ap;
                unsigned int u[4] = {(unsigned)p.x,(unsigned)p.y,(unsigned)p.z,(unsigned)p.w};
#pragma unroll
                for (int j = 0; j < 4; j++) {
                    av[2*j]   = bf2f((unsigned short)(u[j] & 0xffffu));
                    av[2*j+1] = bf2f((unsigned short)(u[j] >> 16));
                }
            }
        }
#pragma unroll
        for (int j = 0; j < 8; j++) Ast[ak + j][ar] = av[j];
        float bv[8];
        {
            size_t off = boff + (size_t)(k0 + bk) * N + n0 + bn;
            if (isf) {
                const float* bp = (const float*)Bb + off;
                float4 p0 = *(const float4*)bp, p1 = *((const float4*)bp + 1);
                bv[0]=p0.x; bv[1]=p0.y; bv[2]=p0.z; bv[3]=p0.w;
                bv[4]=p1.x; bv[5]=p1.y; bv[6]=p1.z; bv[7]=p1.w;
            } else {
                const unsigned short* bp = (const unsigned short*)Bb + off;
                int4 p = *(const int4*)bp;
                unsigned int u[4] = {(unsigned)p.x,(unsigned)p.y,(unsigned)p.z,(unsigned)p.w};
#pragma unroll
                for (int j = 0; j < 4; j++) {
                    bv[2*j]   = bf2f((unsigned short)(u[j] & 0xffffu));
                    bv[2*j+1] = bf2f((unsigned short)(u[j] >> 16));
                }
            }
        }
#pragma unroll
        for (int j = 0; j < 8; j++) Bs[bk][bn + j] = bv[j];
        __syncthreads();
        const int r0 = (t & 15) * 4, c0 = (t >> 4) * 4;
#pragma unroll
        for (int kk = 0; kk < 32; kk++) {
            float4 a4 = *(const float4*)&Ast[kk][r0];
            float4 b4 = *(const float4*)&Bs[kk][c0];
            double a0=a4.x, a1=a4.y, a2=a4.z, a3=a4.w;
            double b0=b4.x, b1=b4.y, b2=b4.z, b3=b4.w;
            acc[0][0] += a0*b0; acc[0][1] += a0*b1; acc[0][2] += a0*b2; acc[0][3] += a0*b3;
            acc[1][0] += a1*b0; acc[1][1] += a1*b1; acc[1][2] += a1*b2; acc[1][3] += a1*b3;
            acc[2][0] += a2*b0; acc[2][1] += a2*b1; acc[2][2] += a2*b2; acc[2][3] += a2*b3;
            acc[3][0] += a3*b0; acc[3][1] += a3*b1; acc[3][2] += a3*b2; acc[3][3] += a3*b3;
        }
        __syncthreads();
    }
    const int r0 = (t & 15) * 4, c0 = (t >> 4) * 4;
    const size_t czoff = (size_t)blockIdx.z * c_zstr;
#pragma unroll
    for (int i = 0; i < 4; i++)
#pragma unroll
        for (int j = 0; j < 4; j++)
            Cb[czoff + (size_t)(m0 + r0 + i) * N + n0 + c0 + j] = (float)acc[i][j];
}

// ---------------------------------------------------------------------------
// MFMA GEMM with bf16 hi/lo 3-term split: products exact to ~3e-6 rel,
// fp32 accumulation (np-sgemm class). For all post-softmax ops.
// AMODE: 0 = flag-dtype input, 1 = fp32 intermediate. Output fp32.
// ---------------------------------------------------------------------------
template<int AMODE, bool RELU, bool BIAS>
__global__ __launch_bounds__(256) void gemm_hilo(
    const void* __restrict__ Ab, const void* __restrict__ Bb,
    float* __restrict__ Cb, const void* __restrict__ bias,
    const int* __restrict__ flags,
    int N, int Kd, long long a_bstr, long long b_hstr, long long c_zstr, int NH)
{
    const int isf = flags[0];
    const int aIsF32 = (AMODE == 1) ? 1 : isf;
    __shared__ unsigned short a_hi[64][40], a_lo[64][40];
    __shared__ unsigned short b_hi[64][40], b_lo[64][40];

    const int tid = threadIdx.x;
    const int w = tid >> 6, l = tid & 63;
    const int lq = l & 15, quad = l >> 4;
    const int m0 = blockIdx.x * 64, n0 = blockIdx.y * 64;
    const int zb = blockIdx.z / NH, zh = blockIdx.z % NH;
    const size_t aoff = (size_t)zb * a_bstr, boff = (size_t)zh * b_hstr;

    f32x4 acc[4] = { {0,0,0,0},{0,0,0,0},{0,0,0,0},{0,0,0,0} };
    const int arow = tid >> 2, ac8 = (tid & 3) * 8;
    const int bk = tid >> 3, bn8 = (tid & 7) * 8;

    for (int k0 = 0; k0 < Kd; k0 += 32) {
        // ---- stage A (hi/lo) ----
        {
            size_t off = aoff + (size_t)(m0 + arow) * Kd + k0 + ac8;
            unsigned short hh[8], ll[8];
            if (aIsF32) {
                const float* ap = (const float*)Ab + off;
                float4 p0 = *(const float4*)ap, p1 = *((const float4*)ap + 1);
                float vv[8] = {p0.x,p0.y,p0.z,p0.w,p1.x,p1.y,p1.z,p1.w};
#pragma unroll
                for (int j = 0; j < 8; j++) {
                    hh[j] = f2bf(vv[j]);
                    ll[j] = f2bf(vv[j] - bf2f(hh[j]));
                }
            } else {
                int4 p = *(const int4*)((const unsigned short*)Ab + off);
                unsigned int u[4] = {(unsigned)p.x,(unsigned)p.y,(unsigned)p.z,(unsigned)p.w};
#pragma unroll
                for (int j = 0; j < 4; j++) {
                    hh[2*j]   = (unsigned short)(u[j] & 0xffffu);
                    hh[2*j+1] = (unsigned short)(u[j] >> 16);
                    ll[2*j] = 0; ll[2*j+1] = 0;
                }
            }
            int4 ph, pl;
            ph.x = (int)((unsigned)hh[0] | ((unsigned)hh[1] << 16));
            ph.y = (int)((unsigned)hh[2] | ((unsigned)hh[3] << 16));
            ph.z = (int)((unsigned)hh[4] | ((unsigned)hh[5] << 16));
            ph.w = (int)((unsigned)hh[6] | ((unsigned)hh[7] << 16));
            pl.x = (int)((unsigned)ll[0] | ((unsigned)ll[1] << 16));
            pl.y = (int)((unsigned)ll[2] | ((unsigned)ll[3] << 16));
            pl.z = (int)((unsigned)ll[4] | ((unsigned)ll[5] << 16));
            pl.w = (int)((unsigned)ll[6] | ((unsigned)ll[7] << 16));
            *(int4*)&a_hi[arow][ac8] = ph;
            *(int4*)&a_lo[arow][ac8] = pl;
        }
        // ---- stage B (hi/lo, transpose to [n][k]) ----
        {
            size_t off = boff + (size_t)(k0 + bk) * N + n0 + bn8;
            unsigned short hh[8], ll[8];
            if (isf) {
                const float* bp = (const float*)Bb + off;
                float4 p0 = *(const float4*)bp, p1 = *((const float4*)bp + 1);
                float vv[8] = {p0.x,p0.y,p0.z,p0.w,p1.x,p1.y,p1.z,p1.w};
#pragma unroll
                for (int j = 0; j < 8; j++) {
                    hh[j] = f2bf(vv[j]);
                    ll[j] = f2bf(vv[j] - bf2f(hh[j]));
                }
            } else {
                int4 p = *(const int4*)((const unsigned short*)Bb + off);
                unsigned int u[4] = {(unsigned)p.x,(unsigned)p.y,(unsigned)p.z,(unsigned)p.w};
#pragma unroll
                for (int j = 0; j < 4; j++) {
                    hh[2*j]   = (unsigned short)(u[j] & 0xffffu);
                    hh[2*j+1] = (unsigned short)(u[j] >> 16);
                    ll[2*j] = 0; ll[2*j+1] = 0;
                }
            }
#pragma unroll
            for (int j = 0; j < 8; j++) {
                b_hi[bn8 + j][bk] = hh[j];
                b_lo[bn8 + j][bk] = ll[j];
            }
        }
        __syncthreads();
        bf16x8 ah = *(bf16x8*)&a_hi[w * 16 + lq][quad * 8];
        bf16x8 al = *(bf16x8*)&a_lo[w * 16 + lq][quad * 8];
#pragma unroll
        for (int nt = 0; nt < 4; nt++) {
            bf16x8 bh = *(bf16x8*)&b_hi[nt * 16 + lq][quad * 8];
            bf16x8 bl = *(bf16x8*)&b_lo[nt * 16 + lq][quad * 8];
            acc[nt] = __builtin_amdgcn_mfma_f32_16x16x32_bf16(ah, bh, acc[nt], 0, 0, 0);
            acc[nt] = __builtin_amdgcn_mfma_f32_16x16x32_bf16(ah, bl, acc[nt], 0, 0, 0);
            acc[nt] = __builtin_amdgcn_mfma_f32_16x16x32_bf16(al, bh, acc[nt], 0, 0, 0);
        }
        __syncthreads();
    }

    // epilogue: C/D layout col=lane&15, row=quad*4+reg (m89-verified)
    const int rowb = m0 + w * 16 + quad * 4;
    const size_t czoff = (size_t)blockIdx.z * c_zstr;
#pragma unroll
    for (int nt = 0; nt < 4; nt++) {
        int col = n0 + nt * 16 + lq;
        float bv = BIAS ? ldflag(bias, col, isf) : 0.0f;
#pragma unroll
        for (int r = 0; r < 4; r++) {
            float val = acc[nt][r] + bv;
            if (RELU) val = fmaxf(val, 0.0f);
            Cb[czoff + (size_t)(rowb + r) * N + col] = val;
        }
    }
}

// ---------------------------------------------------------------------------
// Attention, single fp64 logit sweep. Block = 4 query rows of one (b,h);
// wave w owns row d0+w. K/V staged in LDS tiles of 128 rows (stride 65 ->
// conflict-free). Logits in registers (32 doubles/lane), fp64 exp, fp32 PV.
// Mask quirk faithful: -100 on UNSCALED logit when c <= d, then *0.125.
// ---------------------------------------------------------------------------
__global__ __launch_bounds__(256) void attn_prec(
    const float* __restrict__ q, const float* __restrict__ k,
    const float* __restrict__ v, float* __restrict__ pre, int masked)
{
    __shared__ float  kv[128][65];   // 33.3 KB (K tiles, then V tiles)
    __shared__ double sqd[4][KV_];   // 2 KB
    __shared__ float  sp[4][C_];     // 32 KB

    const int idx = blockIdx.x;
    const int d0 = (idx & (C_ / 4 - 1)) * 4;
    const int h = (idx >> 9) & (H_ - 1);
    const int b = idx >> 13;
    const size_t bh = (size_t)(b * H_ + h);
    const float* Q = q + (bh * C_ + d0) * KV_;
    const float* K = k + bh * C_ * KV_;
    const float* V = v + bh * C_ * KV_;
    const int tid = threadIdx.x;
    const int w = tid >> 6, l = tid & 63;
    const int d = d0 + w;
    const int crow = tid >> 1;          // 0..127 (staging row)
    const int cj0 = (tid & 1) * 32;     // staging col offset

    sqd[w][l] = (double)Q[w * KV_ + l];
    __syncthreads();

    double sreg[32];
    double m = -1e300;
#pragma unroll
    for (int t16 = 0; t16 < 16; t16++) {
        const int c0 = t16 * 128;
        const float* Ksrc = K + (size_t)(c0 + crow) * KV_ + cj0;
#pragma unroll
        for (int i = 0; i < 8; i++) {
            float4 p4 = *(const float4*)(Ksrc + 4 * i);
            kv[crow][cj0 + 4*i + 0] = p4.x;
            kv[crow][cj0 + 4*i + 1] = p4.y;
            kv[crow][cj0 + 4*i + 2] = p4.z;
            kv[crow][cj0 + 4*i + 3] = p4.w;
        }
        __syncthreads();
        double sA = 0.0, sB = 0.0;
#pragma unroll 8
        for (int j = 0; j < KV_; j++) {
            double qj = sqd[w][j];
            sA += (double)kv[l][j] * qj;
            sB += (double)kv[64 + l][j] * qj;
        }
        if (masked) {
            if (c0 + l <= d) sA -= 100.0;
            if (c0 + 64 + l <= d) sB -= 100.0;
        }
        sreg[2 * t16] = sA; sreg[2 * t16 + 1] = sB;
        m = fmax(m, fmax(sA, sB));
        __syncthreads();
    }
#pragma unroll
    for (int off = 32; off > 0; off >>= 1) m = fmax(m, __shfl_down(m, off, 64));
    m = __shfl(m, 0, 64);

    double S = 0.0;
#pragma unroll
    for (int i = 0; i < 32; i++) {
        double p = exp(0.125 * (sreg[i] - m));
        S += p;
        sp[w][(i >> 1) * 128 + (i & 1) * 64 + l] = (float)p;
    }
#pragma unroll
    for (int off = 32; off > 0; off >>= 1) S += __shfl_down(S, off, 64);
    S = __shfl(S, 0, 64);

    float o = 0.0f;
    for (int t16 = 0; t16 < 16; t16++) {
        const int c0 = t16 * 128;
        __syncthreads();
        const float* Vsrc = V + (size_t)(c0 + crow) * KV_ + cj0;
#pragma unroll
        for (int i = 0; i < 8; i++) {
            float4 p4 = *(const float4*)(Vsrc + 4 * i);
            kv[crow][cj0 + 4*i + 0] = p4.x;
            kv[crow][cj0 + 4*i + 1] = p4.y;
            kv[crow][cj0 + 4*i + 2] = p4.z;
            kv[crow][cj0 + 4*i + 3] = p4.w;
        }
        __syncthreads();
#pragma unroll 16
        for (int cl = 0; cl < 128; cl++)
            o += sp[w][c0 + cl] * kv[cl][l];
    }
    float out = (float)((double)o / S);
    pre[(((size_t)b * C_ + d) * H_ + h) * KV_ + l] = out;
}

// ---------------------------------------------------------------------------
// Residual + LayerNorm, fp64 stats, fp32 storage. In-place safe.
// IN1MODE: 0 = flag-dtype input, 1 = fp32 intermediate.
// OUTMODE: 0 = fp32, 1 = flag-dtype (d_out).
// ---------------------------------------------------------------------------
template<int IN1MODE, int OUTMODE>
__global__ __launch_bounds__(256) void ln_f64(
    const void* __restrict__ in1, const float* __restrict__ in2,
    const void* __restrict__ g, const void* __restrict__ b,
    void* __restrict__ out, const int* __restrict__ flags)
{
    __shared__ double buf[M_];
    __shared__ double red[4];
    const int isf = flags[0];
    const int row = blockIdx.x;
    const size_t base = (size_t)row * M_;
    const int tid = threadIdx.x;
    double s = 0.0;
    for (int i = tid; i < M_; i += 256) {
        double v1 = (IN1MODE == 1) ? (double)((const float*)in1)[base + i]
                                   : (double)ldflag(in1, base + i, isf);
        double val = v1 + (double)in2[base + i];
        buf[i] = val;
        s += val;
    }
    s = blockReduceSumD(s, red, tid);
    const double mu = s * (1.0 / M_);
    double vs = 0.0;
    for (int i = tid; i < M_; i += 256) { double dd = buf[i] - mu; vs += dd * dd; }
    vs = blockReduceSumD(vs, red, tid);
    const double rstd = 1.0 / sqrt(vs * (1.0 / M_) + 1e-5);
    for (int i = tid; i < M_; i += 256) {
        double y = (buf[i] - mu) * rstd * (double)ldflag(g, i, isf) + (double)ldflag(b, i, isf);
        if (OUTMODE == 0) ((float*)out)[base + i] = (float)y;
        else if (isf)     ((float*)out)[base + i] = (float)y;
        else              ((unsigned short*)out)[base + i] = f2bf((float)y);
    }
}

// ---------------------------------------------------------------------------
extern "C" void kernel_launch(void* const* d_in, const int* in_sizes, int n_in,
                              void* d_out, int out_size, void* d_ws, size_t ws_size,
                              hipStream_t stream)
{
    const void* enc = d_in[0];
    const void* x   = d_in[1];
    const void* wq1 = d_in[2];
    const void* wk1 = d_in[3];
    const void* wv1 = d_in[4];
    const void* wo1 = d_in[5];
    const void* g1  = d_in[6];
    const void* b1  = d_in[7];
    const void* wq2 = d_in[8];
    const void* wk2 = d_in[9];
    const void* wv2 = d_in[10];
    const void* wo2 = d_in[11];
    const void* g2  = d_in[12];
    const void* b2  = d_in[13];
    const void* fw1 = d_in[14];
    const void* fb1 = d_in[15];
    const void* fw2 = d_in[16];
    const void* fb2 = d_in[17];
    const void* g3  = d_in[18];
    const void* b3  = d_in[19];

    int* fl = (int*)d_ws;
    const size_t NQ = (size_t)B_ * C_ * M_;            // 4,194,304
    // Same aliasing as the PASSING round 5:
    // S0: q1/q2 -> h1[0] | S1: k1->attout1->k2->attout2 -> h1[1]
    // S2: v1->v2 -> h1[2] | S3: pre1->pre2 -> h1[3] | S4: n1 -> n2 (in-place)
    // ff lives in d_out; LN3 in-place on d_out.
    float* S0 = (float*)((char*)d_ws + 4096);
    float* S1 = S0 + NQ;
    float* S2 = S1 + NQ;
    float* S3 = S2 + NQ;
    float* S4 = S3 + NQ;
    float* q = S0, *kk = S1, *vv = S2, *pre = S3, *attout = S1, *n1 = S4, *n2 = S4;
    float* h1 = S0;                                    // fp32 [4096,4096] = S0..S3
    float* ff = (float*)d_out;

    dim3 blk(256);
    dim3 gproj(C_ / 64, KV_ / 64, B_ * H_);            // (32,1,32)
    dim3 gout(B_ * C_ / 64, M_ / 64, 1);               // (64,16,1)
    dim3 gffn1(B_ * C_ / 64, F_ / 64, 1);              // (64,64,1)
    dim3 gffn2(B_ * C_ / 64, M_ / 64, 1);              // (64,16,1)
    dim3 gattn(B_ * H_ * (C_ / 4));                    // 16384
    dim3 gln(B_ * C_);                                 // 4096
    const long long AB = (long long)C_ * M_, BH = (long long)M_ * KV_, CZ = (long long)C_ * KV_;

    detect_dtype<<<1, 256, 0, stream>>>((const unsigned int*)wq1, fl);

    // ---- self-attention (masked) ----
    proj_qk64<0><<<gproj, blk, 0, stream>>>(x, wq1, q,  fl, KV_, M_, AB, BH, CZ, H_);
    proj_qk64<0><<<gproj, blk, 0, stream>>>(x, wk1, kk, fl, KV_, M_, AB, BH, CZ, H_);
    gemm_hilo<0,false,false><<<gproj, blk, 0, stream>>>(x, wv1, vv, nullptr, fl, KV_, M_, AB, BH, CZ, H_);
    attn_prec<<<gattn, blk, 0, stream>>>(q, kk, vv, pre, 1);
    gemm_hilo<1,false,false><<<gout, blk, 0, stream>>>(pre, wo1, attout, nullptr, fl, M_, M_, 0, 0, 0, 1);
    ln_f64<0, 0><<<gln, blk, 0, stream>>>(x, attout, g1, b1, n1, fl);

    // ---- cross-attention ----
    proj_qk64<1><<<gproj, blk, 0, stream>>>(n1, wq2, q,  fl, KV_, M_, AB, BH, CZ, H_);
    proj_qk64<0><<<gproj, blk, 0, stream>>>(enc, wk2, kk, fl, KV_, M_, AB, BH, CZ, H_);
    gemm_hilo<0,false,false><<<gproj, blk, 0, stream>>>(enc, wv2, vv, nullptr, fl, KV_, M_, AB, BH, CZ, H_);
    attn_prec<<<gattn, blk, 0, stream>>>(q, kk, vv, pre, 0);
    gemm_hilo<1,false,false><<<gout, blk, 0, stream>>>(pre, wo2, attout, nullptr, fl, M_, M_, 0, 0, 0, 1);
    ln_f64<1, 0><<<gln, blk, 0, stream>>>(n1, attout, g2, b2, n2, fl);   // in-place S4

    // ---- FFN (h1 fp32 spans S0..S3; ff in d_out; LN3 in-place) ----
    gemm_hilo<1,true,true><<<gffn1, blk, 0, stream>>>(n2, fw1, h1, fb1, fl, F_, M_, 0, 0, 0, 1);
    gemm_hilo<1,false,true><<<gffn2, blk, 0, stream>>>(h1, fw2, ff, fb2, fl, M_, F_, 0, 0, 0, 1);
    ln_f64<1, 1><<<gln, blk, 0, stream>>>(n2, ff, g3, b3, d_out, fl);
}

// Round 7
// 3656.805 us; speedup vs baseline: 6.3422x; 2.0882x over previous
//
#include <hip/hip_runtime.h>
#include <math.h>

// Problem dims (fixed)
#define B_ 2
#define C_ 2048
#define M_ 1024
#define H_ 16
#define KV_ 64
#define F_ 4096

typedef __attribute__((ext_vector_type(8))) __bf16 bf16x8;
typedef __attribute__((ext_vector_type(4))) float f32x4;

__device__ __forceinline__ float bf2f(unsigned short u) {
    union { unsigned int i; float f; } x; x.i = ((unsigned int)u) << 16; return x.f;
}
__device__ __forceinline__ unsigned short f2bf(float f) {
    union { float f; unsigned int i; } x; x.f = f;
    unsigned int r = x.i + 0x7fffu + ((x.i >> 16) & 1u);
    return (unsigned short)(r >> 16);
}
__device__ __forceinline__ float ldflag(const void* p, size_t i, int isf) {
    return isf ? ((const float*)p)[i] : bf2f(((const unsigned short*)p)[i]);
}

__device__ __forceinline__ double blockReduceSumD(double v, double* red, int tid) {
#pragma unroll
    for (int off = 32; off > 0; off >>= 1) v += __shfl_down(v, off, 64);
    if ((tid & 63) == 0) red[tid >> 6] = v;
    __syncthreads();
    v = red[0] + red[1] + red[2] + red[3];
    __syncthreads();
    return v;
}

// ---------------------------------------------------------------------------
// Input-dtype detector (fires fp32 on this harness). flags[0]=1 iff fp32.
// ---------------------------------------------------------------------------
__global__ void detect_dtype(const unsigned int* __restrict__ w, int* __restrict__ flags) {
    __shared__ int cnt[256];
    int t = threadIdx.x, c = 0;
    for (int i = t; i < 2048; i += 256) {
        unsigned int e = (w[i] >> 7) & 0xffu;
        if (e >= 140u || (e > 0u && e < 91u)) c++;
    }
    cnt[t] = c; __syncthreads();
    for (int s = 128; s > 0; s >>= 1) { if (t < s) cnt[t] += cnt[t + s]; __syncthreads(); }
    if (t == 0) flags[0] = (cnt[0] > 300) ? 1 : 0;
}

// ---------------------------------------------------------------------------
// Q/K projection GEMM: fp64 ACCUMULATION, fp32 LDS tiles.
// AMODE: 0 = flag-dtype input, 1 = fp32 intermediate. Output fp32.
// Tile 64x64x32, 16x16 threads x 4x4 each.  (unchanged from passing round 6)
// ---------------------------------------------------------------------------
template<int AMODE>
__global__ __launch_bounds__(256) void proj_qk64(
    const void* __restrict__ Ab, const void* __restrict__ Bb,
    float* __restrict__ Cb, const int* __restrict__ flags,
    int N, int Kd, long long a_bstr, long long b_hstr, long long c_zstr, int NH)
{
    const int isf = flags[0];
    const int isfA = (AMODE == 1) ? 1 : isf;
    __shared__ float Ast[32][65];   // [k][m]
    __shared__ float Bs[32][65];    // [k][n]
    const int t = threadIdx.x;
    const int m0 = blockIdx.x * 64, n0 = blockIdx.y * 64;
    const int zb = blockIdx.z / NH, zh = blockIdx.z % NH;
    const size_t aoff = (size_t)zb * a_bstr, boff = (size_t)zh * b_hstr;

    double acc[4][4] = {};
    const int ar = t >> 2, ak = (t & 3) * 8;
    const int bk = t >> 3, bn = (t & 7) * 8;

    for (int k0 = 0; k0 < Kd; k0 += 32) {
        float av[8];
        {
            size_t off = aoff + (size_t)(m0 + ar) * Kd + k0 + ak;
            if (isfA) {
                const float* ap = (const float*)Ab + off;
                float4 p0 = *(const float4*)ap, p1 = *((const float4*)ap + 1);
                av[0]=p0.x; av[1]=p0.y; av[2]=p0.z; av[3]=p0.w;
                av[4]=p1.x; av[5]=p1.y; av[6]=p1.z; av[7]=p1.w;
            } else {
                const unsigned short* ap = (const unsigned short*)Ab + off;
                int4 p = *(const int4*)ap;
                unsigned int u[4] = {(unsigned)p.x,(unsigned)p.y,(unsigned)p.z,(unsigned)p.w};
#pragma unroll
                for (int j = 0; j < 4; j++) {
                    av[2*j]   = bf2f((unsigned short)(u[j] & 0xffffu));
                    av[2*j+1] = bf2f((unsigned short)(u[j] >> 16));
                }
            }
        }
#pragma unroll
        for (int j = 0; j < 8; j++) Ast[ak + j][ar] = av[j];
        float bv[8];
        {
            size_t off = boff + (size_t)(k0 + bk) * N + n0 + bn;
            if (isf) {
                const float* bp = (const float*)Bb + off;
                float4 p0 = *(const float4*)bp, p1 = *((const float4*)bp + 1);
                bv[0]=p0.x; bv[1]=p0.y; bv[2]=p0.z; bv[3]=p0.w;
                bv[4]=p1.x; bv[5]=p1.y; bv[6]=p1.z; bv[7]=p1.w;
            } else {
                const unsigned short* bp = (const unsigned short*)Bb + off;
                int4 p = *(const int4*)bp;
                unsigned int u[4] = {(unsigned)p.x,(unsigned)p.y,(unsigned)p.z,(unsigned)p.w};
#pragma unroll
                for (int j = 0; j < 4; j++) {
                    bv[2*j]   = bf2f((unsigned short)(u[j] & 0xffffu));
                    bv[2*j+1] = bf2f((unsigned short)(u[j] >> 16));
                }
            }
        }
#pragma unroll
        for (int j = 0; j < 8; j++) Bs[bk][bn + j] = bv[j];
        __syncthreads();
        const int r0 = (t & 15) * 4, c0 = (t >> 4) * 4;
#pragma unroll
        for (int kk = 0; kk < 32; kk++) {
            float4 a4 = *(const float4*)&Ast[kk][r0];
            float4 b4 = *(const float4*)&Bs[kk][c0];
            double a0=a4.x, a1=a4.y, a2=a4.z, a3=a4.w;
            double b0=b4.x, b1=b4.y, b2=b4.z, b3=b4.w;
            acc[0][0] += a0*b0; acc[0][1] += a0*b1; acc[0][2] += a0*b2; acc[0][3] += a0*b3;
            acc[1][0] += a1*b0; acc[1][1] += a1*b1; acc[1][2] += a1*b2; acc[1][3] += a1*b3;
            acc[2][0] += a2*b0; acc[2][1] += a2*b1; acc[2][2] += a2*b2; acc[2][3] += a2*b3;
            acc[3][0] += a3*b0; acc[3][1] += a3*b1; acc[3][2] += a3*b2; acc[3][3] += a3*b3;
        }
        __syncthreads();
    }
    const int r0 = (t & 15) * 4, c0 = (t >> 4) * 4;
    const size_t czoff = (size_t)blockIdx.z * c_zstr;
#pragma unroll
    for (int i = 0; i < 4; i++)
#pragma unroll
        for (int j = 0; j < 4; j++)
            Cb[czoff + (size_t)(m0 + r0 + i) * N + n0 + c0 + j] = (float)acc[i][j];
}

// ---------------------------------------------------------------------------
// MFMA GEMM with bf16 hi/lo 3-term split (post-softmax ops). Unchanged.
// ---------------------------------------------------------------------------
template<int AMODE, bool RELU, bool BIAS>
__global__ __launch_bounds__(256) void gemm_hilo(
    const void* __restrict__ Ab, const void* __restrict__ Bb,
    float* __restrict__ Cb, const void* __restrict__ bias,
    const int* __restrict__ flags,
    int N, int Kd, long long a_bstr, long long b_hstr, long long c_zstr, int NH)
{
    const int isf = flags[0];
    const int aIsF32 = (AMODE == 1) ? 1 : isf;
    __shared__ unsigned short a_hi[64][40], a_lo[64][40];
    __shared__ unsigned short b_hi[64][40], b_lo[64][40];

    const int tid = threadIdx.x;
    const int w = tid >> 6, l = tid & 63;
    const int lq = l & 15, quad = l >> 4;
    const int m0 = blockIdx.x * 64, n0 = blockIdx.y * 64;
    const int zb = blockIdx.z / NH, zh = blockIdx.z % NH;
    const size_t aoff = (size_t)zb * a_bstr, boff = (size_t)zh * b_hstr;

    f32x4 acc[4] = { {0,0,0,0},{0,0,0,0},{0,0,0,0},{0,0,0,0} };
    const int arow = tid >> 2, ac8 = (tid & 3) * 8;
    const int bk = tid >> 3, bn8 = (tid & 7) * 8;

    for (int k0 = 0; k0 < Kd; k0 += 32) {
        {
            size_t off = aoff + (size_t)(m0 + arow) * Kd + k0 + ac8;
            unsigned short hh[8], ll[8];
            if (aIsF32) {
                const float* ap = (const float*)Ab + off;
                float4 p0 = *(const float4*)ap, p1 = *((const float4*)ap + 1);
                float vv[8] = {p0.x,p0.y,p0.z,p0.w,p1.x,p1.y,p1.z,p1.w};
#pragma unroll
                for (int j = 0; j < 8; j++) {
                    hh[j] = f2bf(vv[j]);
                    ll[j] = f2bf(vv[j] - bf2f(hh[j]));
                }
            } else {
                int4 p = *(const int4*)((const unsigned short*)Ab + off);
                unsigned int u[4] = {(unsigned)p.x,(unsigned)p.y,(unsigned)p.z,(unsigned)p.w};
#pragma unroll
                for (int j = 0; j < 4; j++) {
                    hh[2*j]   = (unsigned short)(u[j] & 0xffffu);
                    hh[2*j+1] = (unsigned short)(u[j] >> 16);
                    ll[2*j] = 0; ll[2*j+1] = 0;
                }
            }
            int4 ph, pl;
            ph.x = (int)((unsigned)hh[0] | ((unsigned)hh[1] << 16));
            ph.y = (int)((unsigned)hh[2] | ((unsigned)hh[3] << 16));
            ph.z = (int)((unsigned)hh[4] | ((unsigned)hh[5] << 16));
            ph.w = (int)((unsigned)hh[6] | ((unsigned)hh[7] << 16));
            pl.x = (int)((unsigned)ll[0] | ((unsigned)ll[1] << 16));
            pl.y = (int)((unsigned)ll[2] | ((unsigned)ll[3] << 16));
            pl.z = (int)((unsigned)ll[4] | ((unsigned)ll[5] << 16));
            pl.w = (int)((unsigned)ll[6] | ((unsigned)ll[7] << 16));
            *(int4*)&a_hi[arow][ac8] = ph;
            *(int4*)&a_lo[arow][ac8] = pl;
        }
        {
            size_t off = boff + (size_t)(k0 + bk) * N + n0 + bn8;
            unsigned short hh[8], ll[8];
            if (isf) {
                const float* bp = (const float*)Bb + off;
                float4 p0 = *(const float4*)bp, p1 = *((const float4*)bp + 1);
                float vv[8] = {p0.x,p0.y,p0.z,p0.w,p1.x,p1.y,p1.z,p1.w};
#pragma unroll
                for (int j = 0; j < 8; j++) {
                    hh[j] = f2bf(vv[j]);
                    ll[j] = f2bf(vv[j] - bf2f(hh[j]));
                }
            } else {
                int4 p = *(const int4*)((const unsigned short*)Bb + off);
                unsigned int u[4] = {(unsigned)p.x,(unsigned)p.y,(unsigned)p.z,(unsigned)p.w};
#pragma unroll
                for (int j = 0; j < 4; j++) {
                    hh[2*j]   = (unsigned short)(u[j] & 0xffffu);
                    hh[2*j+1] = (unsigned short)(u[j] >> 16);
                    ll[2*j] = 0; ll[2*j+1] = 0;
                }
            }
#pragma unroll
            for (int j = 0; j < 8; j++) {
                b_hi[bn8 + j][bk] = hh[j];
                b_lo[bn8 + j][bk] = ll[j];
            }
        }
        __syncthreads();
        bf16x8 ah = *(bf16x8*)&a_hi[w * 16 + lq][quad * 8];
        bf16x8 al = *(bf16x8*)&a_lo[w * 16 + lq][quad * 8];
#pragma unroll
        for (int nt = 0; nt < 4; nt++) {
            bf16x8 bh = *(bf16x8*)&b_hi[nt * 16 + lq][quad * 8];
            bf16x8 bl = *(bf16x8*)&b_lo[nt * 16 + lq][quad * 8];
            acc[nt] = __builtin_amdgcn_mfma_f32_16x16x32_bf16(ah, bh, acc[nt], 0, 0, 0);
            acc[nt] = __builtin_amdgcn_mfma_f32_16x16x32_bf16(ah, bl, acc[nt], 0, 0, 0);
            acc[nt] = __builtin_amdgcn_mfma_f32_16x16x32_bf16(al, bh, acc[nt], 0, 0, 0);
        }
        __syncthreads();
    }

    const int rowb = m0 + w * 16 + quad * 4;
    const size_t czoff = (size_t)blockIdx.z * c_zstr;
#pragma unroll
    for (int nt = 0; nt < 4; nt++) {
        int col = n0 + nt * 16 + lq;
        float bv = BIAS ? ldflag(bias, col, isf) : 0.0f;
#pragma unroll
        for (int r = 0; r < 4; r++) {
            float val = acc[nt][r] + bv;
            if (RELU) val = fmaxf(val, 0.0f);
            Cb[czoff + (size_t)(rowb + r) * N + col] = val;
        }
    }
}

// ---------------------------------------------------------------------------
// Flash-style attention, fp64 logits. Block = 64 queries x one (b,h);
// keys in 32 tiles of 64. Thread (tq=t&15, tc=t>>4) computes a 4x4 fp64
// logit sub-block GEMM-style from LDS tiles (stride 68: aligned b128,
// 2-way banks = free). Online softmax: m/l/alpha fp32 (scale cancels in
// O/l exactly), exp in fp64 on fp64 logits -> same numerics class as the
// passing two-pass kernel. P reuses the dead K tile. PV = fp32 4x4 GEMM.
// Mask quirk faithful: -100 on UNSCALED logit when key <= query.
// ---------------------------------------------------------------------------
__global__ __launch_bounds__(256) void attn_flash(
    const float* __restrict__ q, const float* __restrict__ k,
    const float* __restrict__ v, float* __restrict__ pre, int masked)
{
    __shared__ float Qs[64][68];    // [j][q]
    __shared__ float KPs[64][68];   // K tile [j][c]; reused as P tile [c][q]
    __shared__ float Vs[64][68];    // [c][v]
    __shared__ float redm[64][17];
    __shared__ float redl[64][17];
    __shared__ float mrow[64], lrow[64], arow[64];

    const int idx = blockIdx.x;
    const int q0 = (idx & (C_ / 64 - 1)) * 64;
    const int h = (idx >> 5) & (H_ - 1);
    const int b = idx >> 9;
    const size_t bh = (size_t)(b * H_ + h);
    const float* Qg = q + (bh * C_ + q0) * KV_;
    const float* Kg = k + bh * C_ * KV_;
    const float* Vg = v + bh * C_ * KV_;
    const int t = threadIdx.x;
    const int tq = t & 15, tc = t >> 4;
    const int srow = t >> 2, scol = (t & 3) * 16;   // staging: row, 16-wide col base

    // stage Q transposed [j][q]
    {
        const float* src = Qg + (size_t)srow * KV_ + scol;
#pragma unroll
        for (int i = 0; i < 4; i++) {
            float4 p4 = *(const float4*)(src + 4 * i);
            Qs[scol + 4*i + 0][srow] = p4.x;
            Qs[scol + 4*i + 1][srow] = p4.y;
            Qs[scol + 4*i + 2][srow] = p4.z;
            Qs[scol + 4*i + 3][srow] = p4.w;
        }
    }
    if (t < 64) { mrow[t] = -3.0e38f; lrow[t] = 0.0f; }

    float O[4][4] = {};

    for (int kt = 0; kt < 32; kt++) {
        const int c0 = kt * 64;
        __syncthreads();   // previous tile's PV reads done before restaging
        {
            const float* ksrc = Kg + (size_t)(c0 + srow) * KV_ + scol;
#pragma unroll
            for (int i = 0; i < 4; i++) {
                float4 p4 = *(const float4*)(ksrc + 4 * i);
                KPs[scol + 4*i + 0][srow] = p4.x;
                KPs[scol + 4*i + 1][srow] = p4.y;
                KPs[scol + 4*i + 2][srow] = p4.z;
                KPs[scol + 4*i + 3][srow] = p4.w;
            }
            const float* vsrc = Vg + (size_t)(c0 + srow) * KV_ + scol;
#pragma unroll
            for (int i = 0; i < 4; i++)
                *(float4*)&Vs[srow][scol + 4 * i] = *(const float4*)(vsrc + 4 * i);
        }
        __syncthreads();

        // S = Q K^T in fp64
        double Sd[4][4] = {};
#pragma unroll 4
        for (int j = 0; j < 64; j++) {
            float4 qa = *(const float4*)&Qs[j][4 * tq];
            float4 kb = *(const float4*)&KPs[j][4 * tc];
            double qd[4] = {qa.x, qa.y, qa.z, qa.w};
            double kd[4] = {kb.x, kb.y, kb.z, kb.w};
#pragma unroll
            for (int i = 0; i < 4; i++)
#pragma unroll
                for (int jj = 0; jj < 4; jj++)
                    Sd[i][jj] += qd[i] * kd[jj];
        }
        if (masked) {
#pragma unroll
            for (int i = 0; i < 4; i++)
#pragma unroll
                for (int jj = 0; jj < 4; jj++)
                    if (c0 + 4 * tc + jj <= q0 + 4 * tq + i) Sd[i][jj] -= 100.0;
        }
        // per-thread row maxes -> redm
#pragma unroll
        for (int i = 0; i < 4; i++) {
            double mm = fmax(fmax(Sd[i][0], Sd[i][1]), fmax(Sd[i][2], Sd[i][3]));
            redm[4 * tq + i][tc] = (float)mm;
        }
        __syncthreads();
        if (t < 64) {
            float tm = redm[t][0];
#pragma unroll
            for (int x = 1; x < 16; x++) tm = fmaxf(tm, redm[t][x]);
            float mo = mrow[t];
            float mn = fmaxf(mo, tm);
            arow[t] = (mo < -1.0e37f) ? 0.0f
                       : (float)exp(0.125 * ((double)mo - (double)mn));
            mrow[t] = mn;
        }
        __syncthreads();
        // P = exp(0.125(S - m)) -> KPs[c][q]; partial row sums -> redl
#pragma unroll
        for (int i = 0; i < 4; i++) {
            double mn = (double)mrow[4 * tq + i];
            float ls = 0.0f;
#pragma unroll
            for (int jj = 0; jj < 4; jj++) {
                float p = (float)exp(0.125 * (Sd[i][jj] - mn));
                KPs[4 * tc + jj][4 * tq + i] = p;
                ls += p;
            }
            redl[4 * tq + i][tc] = ls;
        }
        __syncthreads();   // P tile + redl complete
        if (t < 64) {
            float s = 0.0f;
#pragma unroll
            for (int x = 0; x < 16; x++) s += redl[t][x];
            lrow[t] = lrow[t] * arow[t] + s;
        }
        // O rescale + PV (fp32)
        float al[4];
#pragma unroll
        for (int i = 0; i < 4; i++) al[i] = arow[4 * tq + i];
#pragma unroll
        for (int i = 0; i < 4; i++)
#pragma unroll
            for (int jj = 0; jj < 4; jj++) O[i][jj] *= al[i];
#pragma unroll 4
        for (int c = 0; c < 64; c++) {
            float4 pa = *(const float4*)&KPs[c][4 * tq];
            float4 vb = *(const float4*)&Vs[c][4 * tc];
            float pd[4] = {pa.x, pa.y, pa.z, pa.w};
            float vd[4] = {vb.x, vb.y, vb.z, vb.w};
#pragma unroll
            for (int i = 0; i < 4; i++)
#pragma unroll
                for (int jj = 0; jj < 4; jj++)
                    O[i][jj] += pd[i] * vd[jj];
        }
    }
    __syncthreads();
    // epilogue: out = O / l; pre layout [B, C, H, V]
#pragma unroll
    for (int i = 0; i < 4; i++) {
        float li = lrow[4 * tq + i];
        float4 o4;
        o4.x = O[i][0] / li; o4.y = O[i][1] / li;
        o4.z = O[i][2] / li; o4.w = O[i][3] / li;
        *(float4*)&pre[(((size_t)b * C_ + q0 + 4 * tq + i) * H_ + h) * KV_ + 4 * tc] = o4;
    }
}

// ---------------------------------------------------------------------------
// Residual + LayerNorm, fp64 stats, fp32 storage. In-place safe. Unchanged.
// ---------------------------------------------------------------------------
template<int IN1MODE, int OUTMODE>
__global__ __launch_bounds__(256) void ln_f64(
    const void* __restrict__ in1, const float* __restrict__ in2,
    const void* __restrict__ g, const void* __restrict__ b,
    void* __restrict__ out, const int* __restrict__ flags)
{
    __shared__ double buf[M_];
    __shared__ double red[4];
    const int isf = flags[0];
    const int row = blockIdx.x;
    const size_t base = (size_t)row * M_;
    const int tid = threadIdx.x;
    double s = 0.0;
    for (int i = tid; i < M_; i += 256) {
        double v1 = (IN1MODE == 1) ? (double)((const float*)in1)[base + i]
                                   : (double)ldflag(in1, base + i, isf);
        double val = v1 + (double)in2[base + i];
        buf[i] = val;
        s += val;
    }
    s = blockReduceSumD(s, red, tid);
    const double mu = s * (1.0 / M_);
    double vs = 0.0;
    for (int i = tid; i < M_; i += 256) { double dd = buf[i] - mu; vs += dd * dd; }
    vs = blockReduceSumD(vs, red, tid);
    const double rstd = 1.0 / sqrt(vs * (1.0 / M_) + 1e-5);
    for (int i = tid; i < M_; i += 256) {
        double y = (buf[i] - mu) * rstd * (double)ldflag(g, i, isf) + (double)ldflag(b, i, isf);
        if (OUTMODE == 0) ((float*)out)[base + i] = (float)y;
        else if (isf)     ((float*)out)[base + i] = (float)y;
        else              ((unsigned short*)out)[base + i] = f2bf((float)y);
    }
}

// ---------------------------------------------------------------------------
extern "C" void kernel_launch(void* const* d_in, const int* in_sizes, int n_in,
                              void* d_out, int out_size, void* d_ws, size_t ws_size,
                              hipStream_t stream)
{
    const void* enc = d_in[0];
    const void* x   = d_in[1];
    const void* wq1 = d_in[2];
    const void* wk1 = d_in[3];
    const void* wv1 = d_in[4];
    const void* wo1 = d_in[5];
    const void* g1  = d_in[6];
    const void* b1  = d_in[7];
    const void* wq2 = d_in[8];
    const void* wk2 = d_in[9];
    const void* wv2 = d_in[10];
    const void* wo2 = d_in[11];
    const void* g2  = d_in[12];
    const void* b2  = d_in[13];
    const void* fw1 = d_in[14];
    const void* fb1 = d_in[15];
    const void* fw2 = d_in[16];
    const void* fb2 = d_in[17];
    const void* g3  = d_in[18];
    const void* b3  = d_in[19];

    int* fl = (int*)d_ws;
    const size_t NQ = (size_t)B_ * C_ * M_;            // 4,194,304
    // Same aliasing as the PASSING rounds 5/6:
    // S0: q1/q2 -> h1[0] | S1: k1->attout1->k2->attout2 -> h1[1]
    // S2: v1->v2 -> h1[2] | S3: pre1->pre2 -> h1[3] | S4: n1 -> n2 (in-place)
    // ff lives in d_out; LN3 in-place on d_out.
    float* S0 = (float*)((char*)d_ws + 4096);
    float* S1 = S0 + NQ;
    float* S2 = S1 + NQ;
    float* S3 = S2 + NQ;
    float* S4 = S3 + NQ;
    float* q = S0, *kk = S1, *vv = S2, *pre = S3, *attout = S1, *n1 = S4, *n2 = S4;
    float* h1 = S0;                                    // fp32 [4096,4096] = S0..S3
    float* ff = (float*)d_out;

    dim3 blk(256);
    dim3 gproj(C_ / 64, KV_ / 64, B_ * H_);            // (32,1,32)
    dim3 gout(B_ * C_ / 64, M_ / 64, 1);               // (64,16,1)
    dim3 gffn1(B_ * C_ / 64, F_ / 64, 1);              // (64,64,1)
    dim3 gffn2(B_ * C_ / 64, M_ / 64, 1);              // (64,16,1)
    dim3 gattn(B_ * H_ * (C_ / 64));                   // 1024
    dim3 gln(B_ * C_);                                 // 4096
    const long long AB = (long long)C_ * M_, BH = (long long)M_ * KV_, CZ = (long long)C_ * KV_;

    detect_dtype<<<1, 256, 0, stream>>>((const unsigned int*)wq1, fl);

    // ---- self-attention (masked) ----
    proj_qk64<0><<<gproj, blk, 0, stream>>>(x, wq1, q,  fl, KV_, M_, AB, BH, CZ, H_);
    proj_qk64<0><<<gproj, blk, 0, stream>>>(x, wk1, kk, fl, KV_, M_, AB, BH, CZ, H_);
    gemm_hilo<0,false,false><<<gproj, blk, 0, stream>>>(x, wv1, vv, nullptr, fl, KV_, M_, AB, BH, CZ, H_);
    attn_flash<<<gattn, blk, 0, stream>>>(q, kk, vv, pre, 1);
    gemm_hilo<1,false,false><<<gout, blk, 0, stream>>>(pre, wo1, attout, nullptr, fl, M_, M_, 0, 0, 0, 1);
    ln_f64<0, 0><<<gln, blk, 0, stream>>>(x, attout, g1, b1, n1, fl);

    // ---- cross-attention ----
    proj_qk64<1><<<gproj, blk, 0, stream>>>(n1, wq2, q,  fl, KV_, M_, AB, BH, CZ, H_);
    proj_qk64<0><<<gproj, blk, 0, stream>>>(enc, wk2, kk, fl, KV_, M_, AB, BH, CZ, H_);
    gemm_hilo<0,false,false><<<gproj, blk, 0, stream>>>(enc, wv2, vv, nullptr, fl, KV_, M_, AB, BH, CZ, H_);
    attn_flash<<<gattn, blk, 0, stream>>>(q, kk, vv, pre, 0);
    gemm_hilo<1,false,false><<<gout, blk, 0, stream>>>(pre, wo2, attout, nullptr, fl, M_, M_, 0, 0, 0, 1);
    ln_f64<1, 0><<<gln, blk, 0, stream>>>(n1, attout, g2, b2, n2, fl);   // in-place S4

    // ---- FFN (h1 fp32 spans S0..S3; ff in d_out; LN3 in-place) ----
    gemm_hilo<1,true,true><<<gffn1, blk, 0, stream>>>(n2, fw1, h1, fb1, fl, F_, M_, 0, 0, 0, 1);
    gemm_hilo<1,false,true><<<gffn2, blk, 0, stream>>>(h1, fw2, ff, fb2, fl, M_, F_, 0, 0, 0, 1);
    ln_f64<1, 1><<<gln, blk, 0, stream>>>(n2, ff, g3, b3, d_out, fl);
}